// Round 7
// baseline (232.051 us; speedup 1.0000x reference)
//
#include <hip/hip_runtime.h>
#include <math.h>

// Problem constants (fixed by the reference harness).
constexpr int B = 16;
constexpr int N = 4096;
constexpr int K = 128;

// Native clang vector types — required by __builtin_nontemporal_*.
typedef float fx4 __attribute__((ext_vector_type(4)));
typedef int   ix4 __attribute__((ext_vector_type(4)));

// ---------------------------------------------------------------------------
// Pack kernel: positions [B,N,3] -> padded (x,y,z,0) fx4 [B*N] in d_ws, so a
// neighbor gather is one 16B-aligned global_load_dwordx4. 768 KB working set:
// L2-resident on every XCD, largely L1-hit in the main kernel.
__global__ __launch_bounds__(256)
void pack_positions(const float* __restrict__ pos, fx4* __restrict__ packed) {
    const int t = blockIdx.x * 256 + threadIdx.x;   // 4 atoms per thread
    const fx4* __restrict__ p4 = (const fx4*)pos;
    const fx4 r0 = p4[t * 3 + 0];
    const fx4 r1 = p4[t * 3 + 1];
    const fx4 r2 = p4[t * 3 + 2];
    packed[t * 4 + 0] = (fx4){r0.x, r0.y, r0.z, 0.f};
    packed[t * 4 + 1] = (fx4){r0.w, r1.x, r1.y, 0.f};
    packed[t * 4 + 2] = (fx4){r1.z, r1.w, r2.x, 0.f};
    packed[t * 4 + 3] = (fx4){r2.y, r2.z, r2.w, 0.f};
}

// ---------------------------------------------------------------------------
// Main kernel: no LDS, no barrier. 256-thread blocks (4 waves), 4 elements
// per thread. Streams (nbr/mask/offs/out) use non-temporal loads/stores so
// the read-once data bypasses cache retention and L1 stays dedicated to the
// gathered positions. __launch_bounds__(256,8) -> <=64 VGPR -> 32 waves/CU.
template <bool PACKED>
__global__ __launch_bounds__(256, 8)
void pairwise_dist_g(const fx4*   __restrict__ packed,
                     const float* __restrict__ pos,
                     const int*   __restrict__ nbr,
                     const float* __restrict__ mask,
                     const float* __restrict__ cell,
                     const float* __restrict__ offs,
                     float*       __restrict__ out) {
    const int    t   = blockIdx.x * 256 + threadIdx.x;
    const size_t e0  = (size_t)t * 4;       // 4 consecutive elements
    const int    row = (int)(e0 >> 7);      // global row = b*N + n  (K=128)
    const int    b   = row >> 12;           // (N=4096)

    // Streaming loads (non-temporal).
    const ix4 jj = __builtin_nontemporal_load((const ix4*)(nbr  + e0));
    const fx4 mm = __builtin_nontemporal_load((const fx4*)(mask + e0));
    const fx4 o0 = __builtin_nontemporal_load((const fx4*)(offs + e0 * 3));
    const fx4 o1 = __builtin_nontemporal_load((const fx4*)(offs + e0 * 3 + 4));
    const fx4 o2 = __builtin_nontemporal_load((const fx4*)(offs + e0 * 3 + 8));

    // Center position: one cached dwordx4 (same address across a row's lanes).
    fx4 pi;
    if (PACKED) {
        pi = packed[row];
    } else {
        const float* __restrict__ p = pos + (size_t)row * 3;
        pi = (fx4){p[0], p[1], p[2], 0.f};
    }

    // Cell matrix: wave-uniform per block -> scalar path.
    const float* __restrict__ cb = cell + b * 9;
    const float c00 = cb[0], c01 = cb[1], c02 = cb[2];
    const float c10 = cb[3], c11 = cb[4], c12 = cb[5];
    const float c20 = cb[6], c21 = cb[7], c22 = cb[8];

    const float ox[4] = {o0.x, o0.w, o1.z, o2.y};
    const float oy[4] = {o0.y, o1.x, o1.w, o2.z};
    const float oz[4] = {o0.z, o1.y, o2.x, o2.w};
    const int   j [4] = {jj.x, jj.y, jj.z, jj.w};
    const float m [4] = {mm.x, mm.y, mm.z, mm.w};

    float res[4];
#pragma unroll
    for (int i = 0; i < 4; ++i) {
        fx4 pj;
        if (PACKED) {
            pj = packed[(b << 12) + j[i]];          // one dwordx4, L1/L2-hit
        } else {
            const float* __restrict__ p = pos + ((size_t)(b << 12) + j[i]) * 3;
            pj = (fx4){p[0], p[1], p[2], 0.f};
        }
        const float dx = (pj.x - pi.x) + ox[i] * c00 + oy[i] * c10 + oz[i] * c20;
        const float dy = (pj.y - pi.y) + ox[i] * c01 + oy[i] * c11 + oz[i] * c21;
        const float dz = (pj.z - pi.z) + ox[i] * c02 + oy[i] * c12 + oz[i] * c22;
        const float sq = dx * dx + dy * dy + dz * dz;
        res[i] = (m[i] > 0.0f) ? __builtin_amdgcn_sqrtf(sq) : 0.0f;
    }

    const fx4 r = {res[0], res[1], res[2], res[3]};
    __builtin_nontemporal_store(r, (fx4*)(out + e0));
}

extern "C" void kernel_launch(void* const* d_in, const int* in_sizes, int n_in,
                              void* d_out, int out_size, void* d_ws, size_t ws_size,
                              hipStream_t stream) {
    const float* positions     = (const float*)d_in[0]; // [B,N,3]
    const int*   neighbors     = (const int*)  d_in[1]; // [B,N,K]
    const float* neighbor_mask = (const float*)d_in[2]; // [B,N,K]
    const float* cell          = (const float*)d_in[3]; // [B,3,3]
    const float* cell_offsets  = (const float*)d_in[4]; // [B,N,K,3]
    float*       out           = (float*)d_out;         // [B,N,K]

    const size_t packedBytes = (size_t)B * N * sizeof(fx4);   // 1 MB
    const int    mainBlocks  = (B * N * K) / (256 * 4);       // 8192

    if (ws_size >= packedBytes) {
        fx4* packed = (fx4*)d_ws;
        pack_positions<<<(B * N / 4) / 256, 256, 0, stream>>>(positions, packed);
        pairwise_dist_g<true><<<mainBlocks, 256, 0, stream>>>(
            packed, positions, neighbors, neighbor_mask, cell, cell_offsets, out);
    } else {
        pairwise_dist_g<false><<<mainBlocks, 256, 0, stream>>>(
            nullptr, positions, neighbors, neighbor_mask, cell, cell_offsets, out);
    }
}

// Round 8
// 203.433 us; speedup vs baseline: 1.1407x; 1.1407x over previous
//
#include <hip/hip_runtime.h>
#include <math.h>

// Problem constants (fixed by the reference harness).
constexpr int B = 16;
constexpr int N = 4096;
constexpr int K = 128;

constexpr int ROWS_PER_BLOCK = 128;  // 128 rows x 128 K = 16384 elems/block
constexpr int THREADS = 1024;        // 16 elems/thread: 4 chunks of 4
constexpr int CHUNKS  = 4;
constexpr int WINDOW  = 2;           // rolling lookahead (partially sunk @64 VGPR)

// Native clang vector types — required by __builtin_nontemporal_*.
typedef float fx4 __attribute__((ext_vector_type(4)));
typedef int   ix4 __attribute__((ext_vector_type(4)));

// TLP corner: 512 blocks = 2 blocks/CU (64 KB LDS each, 32 waves/CU = full
// occupancy) + NT streaming + best-effort register window under the 64-VGPR
// cap of __launch_bounds__(1024,8). Whole-batch positions in LDS; gather is
// one ds_read_b128. Tests whether wave-TLP substitutes for the R4 window.

struct Chunk {
    ix4 jj;
    fx4 mm, o0, o1, o2;
};

__device__ __forceinline__ void load_chunk(Chunk& c,
                                           const int*   __restrict__ nbr,
                                           const float* __restrict__ mask,
                                           const float* __restrict__ offs,
                                           size_t e0) {
    c.jj = __builtin_nontemporal_load((const ix4*)(nbr  + e0));
    c.mm = __builtin_nontemporal_load((const fx4*)(mask + e0));
    c.o0 = __builtin_nontemporal_load((const fx4*)(offs + e0 * 3));
    c.o1 = __builtin_nontemporal_load((const fx4*)(offs + e0 * 3 + 4));
    c.o2 = __builtin_nontemporal_load((const fx4*)(offs + e0 * 3 + 8));
}

__global__ __launch_bounds__(THREADS, 8)
void pairwise_dist_tlp(const float* __restrict__ pos,
                       const int*   __restrict__ nbr,
                       const float* __restrict__ mask,
                       const float* __restrict__ cell,
                       const float* __restrict__ offs,
                       float*       __restrict__ out) {
    __shared__ fx4 spos[N];          // 64 KB

    const int tid   = threadIdx.x;
    const int b     = blockIdx.x >> 5;    // 32 blocks per batch
    const int rblk  = blockIdx.x & 31;
    const int nbase = rblk * ROWS_PER_BLOCK;

    // Stage the batch's full positions: 1024 threads x 12 consecutive floats
    // (3x float4), repacked as 4 padded float4 atoms each. Coalesced.
    {
        const fx4* __restrict__ pb4 = (const fx4*)(pos + (size_t)b * N * 3);
        const fx4 r0 = pb4[tid * 3 + 0];
        const fx4 r1 = pb4[tid * 3 + 1];
        const fx4 r2 = pb4[tid * 3 + 2];
        const int a0 = tid * 4;
        spos[a0 + 0] = (fx4){r0.x, r0.y, r0.z, 0.f};
        spos[a0 + 1] = (fx4){r0.w, r1.x, r1.y, 0.f};
        spos[a0 + 2] = (fx4){r1.z, r1.w, r2.x, 0.f};
        spos[a0 + 3] = (fx4){r2.y, r2.z, r2.w, 0.f};
    }

    // Cell matrix: uniform per block -> scalar (s_load) path.
    const float* __restrict__ cb = cell + b * 9;
    const float c00 = cb[0], c01 = cb[1], c02 = cb[2];
    const float c10 = cb[3], c11 = cb[4], c12 = cb[5];
    const float c20 = cb[6], c21 = cb[7], c22 = cb[8];

    const size_t blockElemBase = ((size_t)b * N + nbase) * K;

    // Rolling window: issue WINDOW chunks of loads before first consumption.
    Chunk win[WINDOW];
#pragma unroll
    for (int c = 0; c < WINDOW; ++c)
        load_chunk(win[c], nbr, mask, offs,
                   blockElemBase + (size_t)c * 4096 + (size_t)tid * 4);

    __syncthreads();   // positions ready (after load issue)

#pragma unroll
    for (int c = 0; c < CHUNKS; ++c) {
        const Chunk cur = win[c % WINDOW];

        // Refill the slot we just freed.
        if (c + WINDOW < CHUNKS)
            load_chunk(win[c % WINDOW], nbr, mask, offs,
                       blockElemBase + (size_t)(c + WINDOW) * 4096 +
                       (size_t)tid * 4);

        const int    eLocal = c * 4096 + tid * 4;
        const size_t e0     = blockElemBase + eLocal;
        const int    n      = nbase + (eLocal >> 7);   // row (K=128)
        const fx4    pi     = spos[n];

        const float ox[4] = {cur.o0.x, cur.o0.w, cur.o1.z, cur.o2.y};
        const float oy[4] = {cur.o0.y, cur.o1.x, cur.o1.w, cur.o2.z};
        const float oz[4] = {cur.o0.z, cur.o1.y, cur.o2.x, cur.o2.w};
        const int   j [4] = {cur.jj.x, cur.jj.y, cur.jj.z, cur.jj.w};
        const float m [4] = {cur.mm.x, cur.mm.y, cur.mm.z, cur.mm.w};

        float res[4];
#pragma unroll
        for (int i = 0; i < 4; ++i) {
            const fx4 pj = spos[j[i]];                 // one ds_read_b128
            const float dx = (pj.x - pi.x) + ox[i] * c00 + oy[i] * c10 + oz[i] * c20;
            const float dy = (pj.y - pi.y) + ox[i] * c01 + oy[i] * c11 + oz[i] * c21;
            const float dz = (pj.z - pi.z) + ox[i] * c02 + oy[i] * c12 + oz[i] * c22;
            const float sq = dx * dx + dy * dy + dz * dz;
            res[i] = (m[i] > 0.0f) ? __builtin_amdgcn_sqrtf(sq) : 0.0f;
        }

        const fx4 r = {res[0], res[1], res[2], res[3]};
        __builtin_nontemporal_store(r, (fx4*)(out + e0));
    }
}

extern "C" void kernel_launch(void* const* d_in, const int* in_sizes, int n_in,
                              void* d_out, int out_size, void* d_ws, size_t ws_size,
                              hipStream_t stream) {
    const float* positions     = (const float*)d_in[0]; // [B,N,3]
    const int*   neighbors     = (const int*)  d_in[1]; // [B,N,K]
    const float* neighbor_mask = (const float*)d_in[2]; // [B,N,K]
    const float* cell          = (const float*)d_in[3]; // [B,3,3]
    const float* cell_offsets  = (const float*)d_in[4]; // [B,N,K,3]
    float*       out           = (float*)d_out;         // [B,N,K]

    const int blocks = B * (N / ROWS_PER_BLOCK);        // 16 * 32 = 512

    pairwise_dist_tlp<<<blocks, THREADS, 0, stream>>>(
        positions, neighbors, neighbor_mask, cell, cell_offsets, out);
}